// Round 1
// 387.958 us; speedup vs baseline: 1.0167x; 1.0167x over previous
//
#include <hip/hip_runtime.h>

#define IN_CH  16
#define HID    8
#define OUT_CH 4
#define N_MID  60
#define BATCH  4194304

// Native clang vector type: __builtin_nontemporal_load/store accept these
// (HIP_vector_type float4 is a struct and is rejected).
typedef float vfloat4 __attribute__((ext_vector_type(4)));

// ---------------------------------------------------------------------------
// Kernel 1: fold the 62-layer affine chain into [4,16] matrix + [4] bias in
// d_ws. Single wave (64 threads): __syncthreads lowers to waitcnt only.
//
// Staging change vs previous version: the stage loops are now FULLY UNROLLED
// with compile-time trip counts. The old `#pragma unroll 1` serialized each
// global_load->ds_write pair at full cold-HBM latency (~15 x ~900cyc+ per
// thread ~= 25 us just to move 17 KB). Unrolled, all 15 dwordx4 loads issue
// back-to-back and retire under one latency shadow (~1-2 us).
// ---------------------------------------------------------------------------
__global__ __launch_bounds__(64) void fold_kernel(
    const float* __restrict__ W1, const float* __restrict__ b1,
    const float* __restrict__ Ws, const float* __restrict__ bs,
    const float* __restrict__ W2, const float* __restrict__ b2,
    float* __restrict__ Mc /* [4*16 + 4] */) {

    __shared__ float sWs[N_MID * HID * HID];   // 15360 B
    __shared__ float sbs[N_MID * HID];         //  1920 B
    __shared__ float A[2][HID][IN_CH];         // running matrix (double buf)
    __shared__ float d[2][HID];                // running bias

    const int t   = threadIdx.x;   // 0..63
    const int col = t & 15;        // 0..15
    const int r0  = t >> 4;        // 0..3 ; thread owns rows r0 and r0+4

    // Stage mid-layer weights/biases into LDS, float4-vectorized, all loads
    // in flight simultaneously (compile-time trip counts -> full unroll).
    {
        const float4* __restrict__ Ws4 = (const float4*)Ws;
        float4*       sW4              = (float4*)sWs;
        #pragma unroll
        for (int j = 0; j < (N_MID * HID * HID / 4) / 64; ++j)   // 15 iters
            sW4[t + j * 64] = Ws4[t + j * 64];

        const float4* __restrict__ bs4 = (const float4*)bs;
        float4*       sb4              = (float4*)sbs;
        // 120 float4s total: iter 0 covers t (all 64 valid), iter 1 guarded.
        sb4[t] = bs4[t];
        if (t < (N_MID * HID / 4) - 64) sb4[t + 64] = bs4[t + 64];
    }

    // init: A = W1 ([8,16] row-major = 32 float4s), d = b1
    if (t < (HID * IN_CH / 4)) ((float4*)&A[0][0][0])[t] = ((const float4*)W1)[t];
    if (t < HID) d[0][t] = b1[t];
    __syncthreads();

    int cur = 0;
    for (int l = 0; l < N_MID; ++l) {
        const float* W = sWs + l * HID * HID;   // [8][8] row-major in LDS
        float a0 = 0.f, a1 = 0.f;
        #pragma unroll
        for (int k = 0; k < HID; ++k) {
            const float av = A[cur][k][col];
            a0 += W[r0 * HID + k]       * av;
            a1 += W[(r0 + 4) * HID + k] * av;
        }
        float bc = 0.f;
        if (t < HID) {
            bc = sbs[l * HID + t];
            #pragma unroll
            for (int k = 0; k < HID; ++k)
                bc += W[t * HID + k] * d[cur][k];
        }
        // write other buffer; reads of A[cur] already done (program order)
        A[1 - cur][r0][col]     = a0;
        A[1 - cur][r0 + 4][col] = a1;
        if (t < HID) d[1 - cur][t] = bc;
        cur ^= 1;
        __syncthreads();   // single barrier per layer (double buffer)
    }

    // final: Mf = W2 @ A -> [4,16] (64 threads cover it exactly)
    {
        const int rr = t >> 4, cc = t & 15;
        float acc = 0.f;
        #pragma unroll
        for (int k = 0; k < HID; ++k)
            acc += W2[rr * HID + k] * A[cur][k][cc];
        Mc[rr * IN_CH + cc] = acc;
    }
    if (t < OUT_CH) {
        float acc = b2[t];
        #pragma unroll
        for (int k = 0; k < HID; ++k)
            acc += W2[t * HID + k] * d[cur][k];
        Mc[OUT_CH * IN_CH + t] = acc;
    }
}

// ---------------------------------------------------------------------------
// Kernel 2: out[i] = Mf @ x[i] + cf. Quad-cooperative, grid-stride x8.
// Lane q of each 4-lane quad loads one float4 (lane-stride 16 B: wave = 1 KB
// contiguous per load), computes the 4 output partials for its quadrant,
// then a 3-shuffle reduce-scatter leaves exactly output q in lane q, stored
// as one contiguous dword per lane. All 8 x-loads issued before compute for
// MLP; nontemporal hints since x/out are pure streaming.
// (UNCHANGED this round — near HBM roofline by construction.)
// ---------------------------------------------------------------------------
#define ITERS 8

__global__ __launch_bounds__(256) void apply_kernel(
    const float* __restrict__ x,
    const float* __restrict__ Mc,
    float* __restrict__ out) {

    const int tid = threadIdx.x;
    const int q   = tid & 3;

    // Per-thread folded-weight slice: M[rr][4q..4q+3] for rr=0..3, + bias q.
    const float4* M4 = (const float4*)Mc;
    const float4 m0 = M4[0 * 4 + q];
    const float4 m1 = M4[1 * 4 + q];
    const float4 m2 = M4[2 * 4 + q];
    const float4 m3 = M4[3 * 4 + q];
    const float  cb = Mc[OUT_CH * IN_CH + q];

    const vfloat4* __restrict__ x4 = (const vfloat4*)x;
    const size_t g0     = (size_t)blockIdx.x * 256 + tid;
    const size_t stride = (size_t)gridDim.x * 256;

    vfloat4 xv[ITERS];
    #pragma unroll
    for (int j = 0; j < ITERS; ++j)
        xv[j] = __builtin_nontemporal_load(&x4[g0 + j * stride]);

    const bool hi2 = (q & 2) != 0;
    const bool lo1 = (q & 1) != 0;

    #pragma unroll
    for (int j = 0; j < ITERS; ++j) {
        const vfloat4 v = xv[j];
        float p0 = m0.x * v.x + m0.y * v.y + m0.z * v.z + m0.w * v.w;
        float p1 = m1.x * v.x + m1.y * v.y + m1.z * v.z + m1.w * v.w;
        float p2 = m2.x * v.x + m2.y * v.y + m2.z * v.z + m2.w * v.w;
        float p3 = m3.x * v.x + m3.y * v.y + m3.z * v.z + m3.w * v.w;

        // Reduce-scatter across the quad: 3 shuffles instead of 8.
        // Round 1 (xor 2): keep outputs {q&2, (q&2)+1}, send the other two.
        float send_a = hi2 ? p0 : p2;
        float send_b = hi2 ? p1 : p3;
        float recv_a = __shfl_xor(send_a, 2);
        float recv_b = __shfl_xor(send_b, 2);
        float k0 = (hi2 ? p2 : p0) + recv_a;   // output (q&2)
        float k1 = (hi2 ? p3 : p1) + recv_b;   // output (q&2)+1
        // Round 2 (xor 1): keep output q.
        float send = lo1 ? k0 : k1;
        float recv = __shfl_xor(send, 1);
        float val  = (lo1 ? k1 : k0) + recv + cb;

        __builtin_nontemporal_store(val, &out[g0 + j * stride]);
    }
}

extern "C" void kernel_launch(void* const* d_in, const int* in_sizes, int n_in,
                              void* d_out, int out_size, void* d_ws, size_t ws_size,
                              hipStream_t stream) {
    const float* x  = (const float*)d_in[0];
    const float* W1 = (const float*)d_in[1];
    const float* b1 = (const float*)d_in[2];
    const float* Ws = (const float*)d_in[3];
    const float* bs = (const float*)d_in[4];
    const float* W2 = (const float*)d_in[5];
    const float* b2 = (const float*)d_in[6];
    float* out = (float*)d_out;
    float* Mc  = (float*)d_ws;   // 68 floats

    fold_kernel<<<1, 64, 0, stream>>>(W1, b1, Ws, bs, W2, b2, Mc);

    // BATCH*IN_CH/4 float4s of x; ITERS per thread, 256 threads/block.
    const int blocks = (BATCH * (IN_CH / 4)) / (256 * ITERS);   // 8192
    apply_kernel<<<blocks, 256, 0, stream>>>(x, Mc, out);
}

// Round 2
// 380.535 us; speedup vs baseline: 1.0365x; 1.0195x over previous
//
#include <hip/hip_runtime.h>

#define IN_CH  16
#define HID    8
#define OUT_CH 4
#define N_MID  60
#define BATCH  4194304

// Native clang vector type: __builtin_nontemporal_load/store accept these
// (HIP_vector_type float4 is a struct and is rejected).
typedef float vfloat4 __attribute__((ext_vector_type(4)));

// ---------------------------------------------------------------------------
// Kernel 1: fold the 62-layer affine chain into [4,16] matrix + [4] bias.
//
// This round: the 60-layer serial chain is split across 4 WAVES (256 thr),
// each folding 15 consecutive layers into a partial affine ENTIRELY IN
// REGISTERS via __shfl (no LDS round-trip, no barriers inside the chain).
// Wave 0 starts from (W1, b1) [8x16]; waves 1..3 start from identity [I|0].
// The 4 partials are then composed in 3 cheap 8x8 LDS steps, and W2/b2
// (prefetched to LDS at kernel start, so no cold-HBM stall in the epilogue)
// produce the final [4,16]+[4].
//
// Register layout per wave: lane = (r0<<4)|col, col=0..15, r0=0..3.
// Lane holds A[r0][col] (a0), A[r0+4][col] (a1) and REDUNDANT per-col bias
// rows d[r0] (dv0), d[r0+4] (dv1)  -> shuffle source for both A[k][col] and
// d[k] is lane ((k&3)<<4)|col  (a0/dv0 for k<4, a1/dv1 for k>=4).
// Per-layer FMA order over k matches the previous version exactly.
// ---------------------------------------------------------------------------
__global__ __launch_bounds__(256) void fold_kernel(
    const float* __restrict__ W1, const float* __restrict__ b1,
    const float* __restrict__ Ws, const float* __restrict__ bs,
    const float* __restrict__ W2, const float* __restrict__ b2,
    float* __restrict__ Mc /* [4*16 + 4] */) {

    __shared__ float sWs[N_MID * HID * HID];   // 15360 B
    __shared__ float sbs[N_MID * HID];         //  1920 B
    __shared__ float sW2[OUT_CH * HID];        //   128 B (prefetched)
    __shared__ float sb2[OUT_CH];
    __shared__ float pA[4][HID][IN_CH];        // per-wave partial matrices
    __shared__ float pv[4][HID];               // per-wave partial biases
    __shared__ float cA[2][HID][IN_CH];        // combine ping-pong
    __shared__ float cv[2][HID];

    const int t   = threadIdx.x;   // 0..255
    const int w   = t >> 6;        // wave 0..3
    const int lid = t & 63;
    const int col = lid & 15;      // 0..15
    const int r0  = lid >> 4;      // 0..3

    // ---- stage everything (all loads in flight together; full unroll) ----
    {
        const float4* __restrict__ Ws4 = (const float4*)Ws;
        float4*       sW4              = (float4*)sWs;
        #pragma unroll
        for (int j = 0; j < 3; ++j)                     // 768 of 960 float4s
            sW4[t + j * 256] = Ws4[t + j * 256];
        if (t < 960 - 768) sW4[t + 768] = Ws4[t + 768];

        const float4* __restrict__ bs4 = (const float4*)bs;
        float4*       sb4              = (float4*)sbs;
        if (t < (N_MID * HID / 4)) sb4[t] = bs4[t];     // 120 float4s

        if (t < OUT_CH * HID) sW2[t] = W2[t];           // epilogue prefetch
        if (t < OUT_CH)       sb2[t] = b2[t];
    }

    // ---- init per-wave chain state (registers) ----
    float a0, a1, dv0, dv1;
    if (w == 0) {
        a0  = W1[r0 * IN_CH + col];
        a1  = W1[(r0 + 4) * IN_CH + col];
        dv0 = b1[r0];
        dv1 = b1[r0 + 4];
    } else {
        a0  = (col == r0)     ? 1.f : 0.f;
        a1  = (col == r0 + 4) ? 1.f : 0.f;
        dv0 = 0.f;
        dv1 = 0.f;
    }
    __syncthreads();   // staged weights visible to all waves

    // ---- 15-layer register chain per wave (no barriers, no LDS writes) ----
    const int base = w * 15;
    #pragma unroll
    for (int l = 0; l < 15; ++l) {
        const float* Wl = sWs + (base + l) * HID * HID;
        const float4 wA = *(const float4*)(Wl + r0 * HID);
        const float4 wB = *(const float4*)(Wl + r0 * HID + 4);
        const float4 wC = *(const float4*)(Wl + (r0 + 4) * HID);
        const float4 wD = *(const float4*)(Wl + (r0 + 4) * HID + 4);
        const float w0[8] = {wA.x, wA.y, wA.z, wA.w, wB.x, wB.y, wB.z, wB.w};
        const float w4[8] = {wC.x, wC.y, wC.z, wC.w, wD.x, wD.y, wD.z, wD.w};

        float na0 = 0.f, na1 = 0.f;
        float nd0 = sbs[(base + l) * HID + r0];
        float nd1 = sbs[(base + l) * HID + r0 + 4];
        #pragma unroll
        for (int k = 0; k < 8; ++k) {
            const int src = ((k & 3) << 4) | col;       // compile-time k
            const float Ak = __shfl((k < 4) ? a0 : a1, src);
            const float dk = __shfl((k < 4) ? dv0 : dv1, src);
            na0 += w0[k] * Ak;
            na1 += w4[k] * Ak;
            nd0 += w0[k] * dk;
            nd1 += w4[k] * dk;
        }
        a0 = na0; a1 = na1; dv0 = nd0; dv1 = nd1;
    }

    // ---- publish partials ----
    pA[w][r0][col]     = a0;
    pA[w][r0 + 4][col] = a1;
    if (col == 0) { pv[w][r0] = dv0; pv[w][r0 + 4] = dv1; }

    // seed combine buffer with partial 0
    if (t < HID * IN_CH) cA[0][t >> 4][t & 15] = 0.f;   // overwritten below
    __syncthreads();
    if (t < HID * IN_CH) cA[0][t >> 4][t & 15] = pA[0][t >> 4][t & 15];
    if (t < HID)         cv[0][t] = pv[0][t];
    __syncthreads();

    // ---- compose: cur <- P_s o cur, s = 1..3 ----
    int cb = 0;
    #pragma unroll
    for (int s = 1; s < 4; ++s) {
        if (t < HID * IN_CH) {
            const int r = t >> 4, c = t & 15;
            float acc = 0.f;
            #pragma unroll
            for (int k = 0; k < HID; ++k)
                acc += pA[s][r][k] * cA[cb][k][c];
            cA[1 - cb][r][c] = acc;
        }
        if (t < HID) {
            float acc = pv[s][t];
            #pragma unroll
            for (int k = 0; k < HID; ++k)
                acc += pA[s][t][k] * cv[cb][k];
            cv[1 - cb][t] = acc;
        }
        cb ^= 1;
        __syncthreads();
    }

    // ---- epilogue: Mc = W2 * cur  (weights already in LDS) ----
    if (t < OUT_CH * IN_CH) {
        const int r = t >> 4, c = t & 15;
        float acc = 0.f;
        #pragma unroll
        for (int k = 0; k < HID; ++k)
            acc += sW2[r * HID + k] * cA[cb][k][c];
        Mc[r * IN_CH + c] = acc;
    }
    if (t < OUT_CH) {
        float acc = sb2[t];
        #pragma unroll
        for (int k = 0; k < HID; ++k)
            acc += sW2[t * HID + k] * cv[cb][k];
        Mc[OUT_CH * IN_CH + t] = acc;
    }
}

// ---------------------------------------------------------------------------
// Kernel 2: out[i] = Mf @ x[i] + cf. Quad-cooperative, grid-stride x8.
// Lane q of each 4-lane quad loads one float4 (lane-stride 16 B: wave = 1 KB
// contiguous per load), computes the 4 output partials for its quadrant,
// then a 3-shuffle reduce-scatter leaves exactly output q in lane q, stored
// as one contiguous dword per lane. All 8 x-loads issued before compute for
// MLP; nontemporal hints since x/out are pure streaming.
// (UNCHANGED — at HBM roofline: 335 MB @ ~6.5 TB/s ~= 52 us floor.)
// ---------------------------------------------------------------------------
#define ITERS 8

__global__ __launch_bounds__(256) void apply_kernel(
    const float* __restrict__ x,
    const float* __restrict__ Mc,
    float* __restrict__ out) {

    const int tid = threadIdx.x;
    const int q   = tid & 3;

    // Per-thread folded-weight slice: M[rr][4q..4q+3] for rr=0..3, + bias q.
    const float4* M4 = (const float4*)Mc;
    const float4 m0 = M4[0 * 4 + q];
    const float4 m1 = M4[1 * 4 + q];
    const float4 m2 = M4[2 * 4 + q];
    const float4 m3 = M4[3 * 4 + q];
    const float  cb = Mc[OUT_CH * IN_CH + q];

    const vfloat4* __restrict__ x4 = (const vfloat4*)x;
    const size_t g0     = (size_t)blockIdx.x * 256 + tid;
    const size_t stride = (size_t)gridDim.x * 256;

    vfloat4 xv[ITERS];
    #pragma unroll
    for (int j = 0; j < ITERS; ++j)
        xv[j] = __builtin_nontemporal_load(&x4[g0 + j * stride]);

    const bool hi2 = (q & 2) != 0;
    const bool lo1 = (q & 1) != 0;

    #pragma unroll
    for (int j = 0; j < ITERS; ++j) {
        const vfloat4 v = xv[j];
        float p0 = m0.x * v.x + m0.y * v.y + m0.z * v.z + m0.w * v.w;
        float p1 = m1.x * v.x + m1.y * v.y + m1.z * v.z + m1.w * v.w;
        float p2 = m2.x * v.x + m2.y * v.y + m2.z * v.z + m2.w * v.w;
        float p3 = m3.x * v.x + m3.y * v.y + m3.z * v.z + m3.w * v.w;

        // Reduce-scatter across the quad: 3 shuffles instead of 8.
        // Round 1 (xor 2): keep outputs {q&2, (q&2)+1}, send the other two.
        float send_a = hi2 ? p0 : p2;
        float send_b = hi2 ? p1 : p3;
        float recv_a = __shfl_xor(send_a, 2);
        float recv_b = __shfl_xor(send_b, 2);
        float k0 = (hi2 ? p2 : p0) + recv_a;   // output (q&2)
        float k1 = (hi2 ? p3 : p1) + recv_b;   // output (q&2)+1
        // Round 2 (xor 1): keep output q.
        float send = lo1 ? k0 : k1;
        float recv = __shfl_xor(send, 1);
        float val  = (lo1 ? k1 : k0) + recv + cb;

        __builtin_nontemporal_store(val, &out[g0 + j * stride]);
    }
}

extern "C" void kernel_launch(void* const* d_in, const int* in_sizes, int n_in,
                              void* d_out, int out_size, void* d_ws, size_t ws_size,
                              hipStream_t stream) {
    const float* x  = (const float*)d_in[0];
    const float* W1 = (const float*)d_in[1];
    const float* b1 = (const float*)d_in[2];
    const float* Ws = (const float*)d_in[3];
    const float* bs = (const float*)d_in[4];
    const float* W2 = (const float*)d_in[5];
    const float* b2 = (const float*)d_in[6];
    float* out = (float*)d_out;
    float* Mc  = (float*)d_ws;   // 68 floats

    fold_kernel<<<1, 256, 0, stream>>>(W1, b1, Ws, bs, W2, b2, Mc);

    // BATCH*IN_CH/4 float4s of x; ITERS per thread, 256 threads/block.
    const int blocks = (BATCH * (IN_CH / 4)) / (256 * ITERS);   // 8192
    apply_kernel<<<blocks, 256, 0, stream>>>(x, Mc, out);
}